// Round 3
// baseline (29.215 us; speedup 1.0000x reference)
//
#include <hip/hip_runtime.h>
#include <math.h>

// ---------------- constants (atomic units) ----------------
constexpr double B2A   = 0.52917721067;
constexpr double H2KJ  = 2625.499638;
constexpr float  RCUT2F = (float)((10.0 / B2A) * (10.0 / B2A));

constexpr double Zc_[2]   = {3.61565, 0.93619};
constexpr double MONO_[2] = {-0.390896, 0.195448};
constexpr double QSH_[2]  = {MONO_[0] - Zc_[0], MONO_[1] - Zc_[1]};
constexpr double DIPO_[2][3] = {{0.0, 0.0, -0.094298},
                                {0.0910288, 0.0, -0.207851}};
constexpr double QS_[2][5] = {{-0.330685, 0.0, 0.0, 0.869923, 0.0},
                              {-0.0739388, 0.0929482, 0.0, 0.00532425, 0.0}};
constexpr double B_EL_[2]  = {2.13358, 2.33322};
constexpr double B_PA_[2]  = {2.1975, 1.96474};
constexpr double SPA_[2]   = {6.50923, 0.527804};
constexpr double KD_PA_[2] = {-5.61925, -0.515584};
constexpr double KQ_PA_[2] = {-1.56567, -0.440164};
constexpr double C6_[2]    = {35.8289, 1.98954};
constexpr double B_D_[2]   = {1.84302, 1.30993};
constexpr double AD_[2][3] = {{4.45992, 6.07259, 4.55391},
                              {2.22001, 1.66835, 0.183855}};
constexpr double ETA_[2]   = {6.18699e-06 * 2.0, 0.561535 * 2.0};
constexpr double B_XP_[2]  = {2.73582, 2.04028};
constexpr double SXP_[2]   = {1.26592, 0.200089};
constexpr double B_CT_[2]  = {1.89485, 2.36763};
constexpr double SACC_[2]  = {-0.67857, 1.36735};
constexpr double SDON_[2]  = {0.757752, 0.00888982};
constexpr double KD_DO_[2] = {-0.512036, -0.0511668};
constexpr double KQ_DO_[2] = {-0.208186, 0.0568152};
constexpr double EPS_OFF = 0.380979;

constexpr double D_M   = 524.265 / H2KJ;
constexpr double K_B   = 5098.15 / H2KJ * B2A * B2A;
constexpr double B_EQ  = 0.958413 / B2A;
constexpr double K_BB  = -61.1423 / H2KJ * B2A * B2A;
constexpr double K_BA  = -159.886 / H2KJ * B2A;
constexpr double TH_EQ = 104.4234 * M_PI / 180.0;
constexpr double K_TH  = 452.183 / H2KJ;
constexpr double SQ32  = 0.86602540378443864676;

// local-frame quadrupole (traceless Cartesian), /3 contraction weight folded in.
// Note q22s == q21s == 0 for both types -> Qxy = Qyz = 0.
constexpr double QLXX_[2] = {(-0.5 * QS_[0][0] + SQ32 * QS_[0][3]) / 3.0,
                             (-0.5 * QS_[1][0] + SQ32 * QS_[1][3]) / 3.0};
constexpr double QLYY_[2] = {(-0.5 * QS_[0][0] - SQ32 * QS_[0][3]) / 3.0,
                             (-0.5 * QS_[1][0] - SQ32 * QS_[1][3]) / 3.0};
constexpr double QLZZ_[2] = {QS_[0][0] / 3.0, QS_[1][0] / 3.0};
constexpr double QLXZ_[2] = {SQ32 * QS_[0][1] / 3.0, SQ32 * QS_[1][1] / 3.0};
// dipole y-component is 0 for both types
constexpr double DIP0_[2] = {DIPO_[0][0], DIPO_[1][0]};
constexpr double DIP2_[2] = {DIPO_[0][2], DIPO_[1][2]};

#define MAXN 768
#define TF(A, t) ((t) ? (float)A[1] : (float)A[0])
#define S(x) (tb ? x##1 : x##0)

// ---------------- f32 vec helpers ----------------
struct f3 { float x, y, z; };
__device__ inline f3 operator-(f3 a, f3 b) { return {a.x - b.x, a.y - b.y, a.z - b.z}; }
__device__ inline f3 operator+(f3 a, f3 b) { return {a.x + b.x, a.y + b.y, a.z + b.z}; }
__device__ inline f3 operator*(f3 a, float s) { return {a.x * s, a.y * s, a.z * s}; }
__device__ inline float dotf(f3 a, f3 b) { return a.x * b.x + a.y * b.y + a.z * b.z; }
__device__ inline f3 crossf(f3 a, f3 b) {
    return {a.y * b.z - a.z * b.y, a.z * b.x - a.x * b.z, a.x * b.y - a.y * b.x};
}
__device__ inline f3 normf(f3 a) { float s = rsqrtf(dotf(a, a)); return a * s; }
__device__ inline f3 getcf(const float* c, int i) {
    return {c[3 * i], c[3 * i + 1], c[3 * i + 2]};
}
__device__ inline void load_boxf(const float* box, float bx[3][3], float bi[3][3]) {
    for (int i = 0; i < 3; ++i)
        for (int j = 0; j < 3; ++j) bx[i][j] = box[i * 3 + j];
    float a = bx[0][0], b = bx[0][1], c = bx[0][2];
    float d = bx[1][0], e = bx[1][1], f = bx[1][2];
    float g = bx[2][0], h = bx[2][1], i2 = bx[2][2];
    float A =  (e * i2 - f * h), B = -(d * i2 - f * g), C =  (d * h - e * g);
    float D = -(b * i2 - c * h), E =  (a * i2 - c * g), F = -(a * h - b * g);
    float G =  (b * f - c * e),  H = -(a * f - c * d),  I =  (a * e - b * d);
    float s = 1.0f / (a * A + b * B + c * C);
    bi[0][0] = A * s; bi[0][1] = D * s; bi[0][2] = G * s;
    bi[1][0] = B * s; bi[1][1] = E * s; bi[1][2] = H * s;
    bi[2][0] = C * s; bi[2][1] = F * s; bi[2][2] = I * s;
}
__device__ inline f3 pbcf(f3 d, const float bx[3][3], const float bi[3][3]) {
    float s0 = rintf(d.x * bi[0][0] + d.y * bi[1][0] + d.z * bi[2][0]);
    float s1 = rintf(d.x * bi[0][1] + d.y * bi[1][1] + d.z * bi[2][1]);
    float s2 = rintf(d.x * bi[0][2] + d.y * bi[1][2] + d.z * bi[2][2]);
    d.x -= s0 * bx[0][0] + s1 * bx[1][0] + s2 * bx[2][0];
    d.y -= s0 * bx[0][1] + s1 * bx[1][1] + s2 * bx[2][1];
    d.z -= s0 * bx[0][2] + s1 * bx[1][2] + s2 * bx[2][2];
    return d;
}
__device__ inline float f1mf(float u) { return -__expf(-u) * (1.0f + 0.5f * u); }  // f1 - 1

// ---------------- f64 helpers (bonded terms only) ----------------
struct d3 { double x, y, z; };
__device__ inline d3 subd(d3 a, d3 b) { return {a.x - b.x, a.y - b.y, a.z - b.z}; }
__device__ inline double dotd(d3 a, d3 b) { return a.x * b.x + a.y * b.y + a.z * b.z; }
__device__ inline d3 getcd(const float* c, int i) {
    return {(double)c[3 * i], (double)c[3 * i + 1], (double)c[3 * i + 2]};
}
__device__ inline void load_boxd(const float* box, double bx[3][3], double bi[3][3]) {
    for (int i = 0; i < 3; ++i)
        for (int j = 0; j < 3; ++j) bx[i][j] = (double)box[i * 3 + j];
    double a = bx[0][0], b = bx[0][1], c = bx[0][2];
    double d = bx[1][0], e = bx[1][1], f = bx[1][2];
    double g = bx[2][0], h = bx[2][1], i2 = bx[2][2];
    double A =  (e * i2 - f * h), B = -(d * i2 - f * g), C =  (d * h - e * g);
    double D = -(b * i2 - c * h), E =  (a * i2 - c * g), F = -(a * h - b * g);
    double G =  (b * f - c * e),  H = -(a * f - c * d),  I =  (a * e - b * d);
    double s = 1.0 / (a * A + b * B + c * C);
    bi[0][0] = A * s; bi[0][1] = D * s; bi[0][2] = G * s;
    bi[1][0] = B * s; bi[1][1] = E * s; bi[1][2] = H * s;
    bi[2][0] = C * s; bi[2][1] = F * s; bi[2][2] = I * s;
}
__device__ inline d3 pbcd(d3 d, const double bx[3][3], const double bi[3][3]) {
    double s0 = rint(d.x * bi[0][0] + d.y * bi[1][0] + d.z * bi[2][0]);
    double s1 = rint(d.x * bi[0][1] + d.y * bi[1][1] + d.z * bi[2][1]);
    double s2 = rint(d.x * bi[0][2] + d.y * bi[1][2] + d.z * bi[2][2]);
    d.x -= s0 * bx[0][0] + s1 * bx[1][0] + s2 * bx[2][0];
    d.y -= s0 * bx[0][1] + s1 * bx[1][1] + s2 * bx[2][1];
    d.z -= s0 * bx[0][2] + s1 * bx[1][2] + s2 * bx[2][2];
    return d;
}

// ---------------- frame (local axes) ----------------
__device__ inline void calc_frame(const float* coords, const float bx[3][3],
                                  const float bi[3][3], int n, float R[3][3], int* tt) {
    int w = n / 3, m = n - w * 3, o = w * 3;
    int zat = (m == 0) ? n + 1 : o;
    int xat = (m == 0) ? n + 2 : ((m == 1) ? n + 1 : n - 1);
    f3 cn = getcf(coords, n);
    f3 uz = normf(pbcf(getcf(coords, zat) - cn, bx, bi));
    f3 ux = normf(pbcf(getcf(coords, xat) - cn, bx, bi));
    f3 zax = (m == 0) ? normf(uz + ux) : uz;
    f3 xax = normf(ux - zax * dotf(ux, zax));
    f3 yax = crossf(zax, xax);
    R[0][0] = xax.x; R[0][1] = yax.x; R[0][2] = zax.x;
    R[1][0] = xax.y; R[1][1] = yax.y; R[1][2] = zax.y;
    R[2][0] = xax.z; R[2][1] = yax.z; R[2][2] = zax.z;
    *tt = (m == 0) ? 0 : 1;
}

__device__ inline double wred(double v) {
    for (int off = 32; off > 0; off >>= 1) v += __shfl_xor(v, off);
    return v;
}

// =============== single fused kernel: 1 wave per atom ===============
__global__ void __launch_bounds__(64) k_fused(const float* __restrict__ coords,
                                              const float* __restrict__ box,
                                              float* __restrict__ out, int N) {
    __shared__ float4 sh[MAXN];   // compacted (dr, b) list
    int a = blockIdx.x;
    int lane = threadIdx.x;
    float bx[3][3], bi[3][3];
    load_boxf(box, bx, bi);

    int wa = a / 3;
    float Ra[3][3]; int ta;
    calc_frame(coords, bx, bi, a, Ra, &ta);
    f3 ca = getcf(coords, a);

    // mu_a (global frame); dipole local y == 0
    float da0 = TF(DIP0_, ta), da2 = TF(DIP2_, ta);
    f3 mua = {Ra[0][0] * da0 + Ra[0][2] * da2,
              Ra[1][0] * da0 + Ra[1][2] * da2,
              Ra[2][0] * da0 + Ra[2][2] * da2};
    // Q_a (global, /3 folded): G = Ra * Ql * Ra^T, Ql has xx,yy,zz,xz only
    float qlxx = TF(QLXX_, ta), qlyy = TF(QLYY_, ta), qlzz = TF(QLZZ_, ta), qlxz = TF(QLXZ_, ta);
    float Bq[3][3];
    for (int i = 0; i < 3; ++i) {
        Bq[i][0] = Ra[i][0] * qlxx + Ra[i][2] * qlxz;
        Bq[i][1] = Ra[i][1] * qlyy;
        Bq[i][2] = Ra[i][0] * qlxz + Ra[i][2] * qlzz;
    }
    float Qaxx = Bq[0][0] * Ra[0][0] + Bq[0][1] * Ra[0][1] + Bq[0][2] * Ra[0][2];
    float Qaxy = Bq[0][0] * Ra[1][0] + Bq[0][1] * Ra[1][1] + Bq[0][2] * Ra[1][2];
    float Qaxz = Bq[0][0] * Ra[2][0] + Bq[0][1] * Ra[2][1] + Bq[0][2] * Ra[2][2];
    float Qayy = Bq[1][0] * Ra[1][0] + Bq[1][1] * Ra[1][1] + Bq[1][2] * Ra[1][2];
    float Qayz = Bq[1][0] * Ra[2][0] + Bq[1][1] * Ra[2][1] + Bq[1][2] * Ra[2][2];
    float Qazz = Bq[2][0] * Ra[2][0] + Bq[2][1] * Ra[2][1] + Bq[2][2] * Ra[2][2];

    // --- type-pair dual constants ---
    float Zi = TF(Zc_, ta), qi = TF(QSH_, ta), qti = Zi + qi;
    float beli = TF(B_EL_, ta);
    float belj0 = (float)B_EL_[0], belj1 = (float)B_EL_[1];
    float bije0 = sqrtf(beli * belj0), bije1 = sqrtf(beli * belj1);
    float qtj0 = (float)(Zc_[0] + QSH_[0]), qtj1 = (float)(Zc_[1] + QSH_[1]);
    float Ziqj0 = Zi * (float)QSH_[0], Ziqj1 = Zi * (float)QSH_[1];
    float Zjqi0 = (float)Zc_[0] * qi, Zjqi1 = (float)Zc_[1] * qi;
    float qiqj0 = qi * (float)QSH_[0], qiqj1 = qi * (float)QSH_[1];
    float qq0 = qti * qtj0, qq1 = qti * qtj1;
    float sacci = TF(SACC_, ta);
    float saccj0 = (float)SACC_[0], saccj1 = (float)SACC_[1];
    float sdi = TF(SDON_, ta), kddi = TF(KD_DO_, ta), kqdi = TF(KQ_DO_, ta);
    float sdj0 = (float)SDON_[0], sdj1 = (float)SDON_[1];
    float kddj0 = (float)KD_DO_[0], kddj1 = (float)KD_DO_[1];
    float kqdj0 = (float)KQ_DO_[0], kqdj1 = (float)KQ_DO_[1];
    float bctt = TF(B_CT_, ta);
    float bijct0 = sqrtf(bctt * (float)B_CT_[0]), bijct1 = sqrtf(bctt * (float)B_CT_[1]);
    float inve0 = (ta == 0) ? 1e-15f : (float)(1.0 / EPS_OFF);
    float inve1 = (ta == 1) ? 1e-15f : (float)(1.0 / EPS_OFF);
    float spi = TF(SPA_, ta), kdpi = TF(KD_PA_, ta), kqpi = TF(KQ_PA_, ta);
    float spj0 = (float)SPA_[0], spj1 = (float)SPA_[1];
    float kdpj0 = (float)KD_PA_[0], kdpj1 = (float)KD_PA_[1];
    float kqpj0 = (float)KQ_PA_[0], kqpj1 = (float)KQ_PA_[1];
    float bpat = TF(B_PA_, ta);
    float bijpa0 = sqrtf(bpat * (float)B_PA_[0]), bijpa1 = sqrtf(bpat * (float)B_PA_[1]);
    float bxpt = TF(B_XP_, ta);
    float bijxp0 = sqrtf(bxpt * (float)B_XP_[0]), bijxp1 = sqrtf(bxpt * (float)B_XP_[1]);
    float sxpi = TF(SXP_, ta);
    float cxp0 = sxpi * (float)SXP_[0], cxp1 = sxpi * (float)SXP_[1];
    float bdt = TF(B_D_, ta);
    float bijd0 = sqrtf(bdt * (float)B_D_[0]), bijd1 = sqrtf(bdt * (float)B_D_[1]);
    float c6t = TF(C6_, ta);
    float c60 = sqrtf(c6t * (float)C6_[0]), c61 = sqrtf(c6t * (float)C6_[1]);
    float dp00 = (float)DIP0_[0], dp01 = (float)DIP0_[1];
    float dp20 = (float)DIP2_[0], dp21 = (float)DIP2_[1];
    float qxx0 = (float)QLXX_[0], qxx1 = (float)QLXX_[1];
    float qyy0 = (float)QLYY_[0], qyy1 = (float)QLYY_[1];
    float qzz0 = (float)QLZZ_[0], qzz1 = (float)QLZZ_[1];
    float qxz0 = (float)QLXZ_[0], qxz1 = (float)QLXZ_[1];

    // ---- phase 1: cutoff compaction into LDS ----
    int cnt = 0;
    int iters = (N + 63) / 64;
    for (int k = 0; k < iters; ++k) {
        int b = lane + 64 * k;
        bool pred = false;
        f3 dr = {0.f, 0.f, 0.f};
        if (b < N) {
            int wb = b / 3;
            dr = pbcf(getcf(coords, b) - ca, bx, bi);
            float r2 = dotf(dr, dr);
            pred = (wb != wa) && (r2 < RCUT2F);
        }
        unsigned long long mask = __ballot(pred);
        int pref = __popcll(mask & ((1ull << lane) - 1ull));
        if (pred) sh[cnt + pref] = make_float4(dr.x, dr.y, dr.z, __int_as_float(b));
        cnt += __popcll(mask);
    }

    // ---- phase 2: dense pair loop over survivors ----
    double e = 0.0, efx = 0.0, efy = 0.0, efz = 0.0, dqa = 0.0;
    for (int i = lane; i < cnt; i += 64) {
        float4 E4 = sh[i];
        f3 dr = {E4.x, E4.y, E4.z};
        int b = __float_as_int(E4.w);
        int wb = b / 3;
        int tb = (b - wb * 3) ? 1 : 0;
        float r2 = dotf(dr, dr);
        float invr = rsqrtf(r2);
        float r = r2 * invr;
        f3 nv = dr * invr;
        float invr2 = invr * invr, invr3 = invr2 * invr;

        // frame of b, then matrix-free multipole contractions: m = Rb^T n
        float Rb[3][3]; int tb2;
        calc_frame(coords, bx, bi, b, Rb, &tb2);
        float mx = Rb[0][0] * nv.x + Rb[1][0] * nv.y + Rb[2][0] * nv.z;
        float my = Rb[0][1] * nv.x + Rb[1][1] * nv.y + Rb[2][1] * nv.z;
        float mz = Rb[0][2] * nv.x + Rb[1][2] * nv.y + Rb[2][2] * nv.z;
        float mujn = S(dp0) * mx + S(dp2) * mz;
        f3 mub = {Rb[0][0] * S(dp0) + Rb[0][2] * S(dp2),
                  Rb[1][0] * S(dp0) + Rb[1][2] * S(dp2),
                  Rb[2][0] * S(dp0) + Rb[2][2] * S(dp2)};
        float nQnj = S(qxx) * mx * mx + S(qyy) * my * my + S(qzz) * mz * mz +
                     2.f * S(qxz) * mx * mz;
        float muin = dotf(mua, nv);
        float nQni = Qaxx * nv.x * nv.x + Qayy * nv.y * nv.y + Qazz * nv.z * nv.z +
                     2.f * (Qaxy * nv.x * nv.y + Qaxz * nv.x * nv.z + Qayz * nv.y * nv.z);

        // permanent electrostatics (e_qq rearranged: no large-term cancellation)
        float fdm = f1mf(S(bije) * r);
        float fd = 1.f + fdm;
        float ep = (S(qq) + S(Ziqj) * f1mf(S(belj) * r) + S(Zjqi) * f1mf(beli * r) +
                    S(qiqj) * fdm) * invr;
        ep += fd * (S(qtj) * muin - qti * mujn) * invr2;
        ep += fd * (dotf(mua, mub) - 3.f * muin * mujn) * invr3;
        ep += 3.f * fd * (qti * nQnj + S(qtj) * nQni) * invr3;

        // field at atom a
        float cc = -S(qtj) * invr2 + 3.f * mujn * invr3;
        efx += (double)(fd * (cc * nv.x - mub.x * invr3));
        efy += (double)(fd * (cc * nv.y - mub.y * invr3));
        efz += (double)(fd * (cc * nv.z - mub.z * invr3));

        // charge transfer
        float sdon_i = sdi + kddi * muin + kqdi * nQni;
        float sdon_j = S(sdj) - S(kddj) * mujn + S(kqdj) * nQnj;
        float sct_r = __expf(-S(bijct) * r) * invr;
        ep -= (sdon_i * S(saccj) + sdon_j * sacci) * sct_r;
        dqa += (double)(sdon_j * sacci * sct_r * S(inve));

        // Pauli repulsion
        float si = spi + kdpi * muin + kqpi * nQni;
        float sj = S(spj) - S(kdpj) * mujn + S(kqpj) * nQnj;
        ep += si * sj * __expf(-S(bijpa) * r) * invr;

        // exchange polarization
        ep -= S(cxp) * __expf(-S(bijxp) * r) * invr;

        // Tang-Toennies dispersion
        float u = S(bijd) * r;
        float poly = 1.f + u * (1.f + u * (0.5f + u * (0.16666667f + u * (4.1666667e-2f +
                     u * (8.3333333e-3f + u * 1.3888889e-3f)))));
        ep -= (1.f - __expf(-u) * poly) * S(c6) * invr3 * invr3;

        e += (double)ep;
    }

    e = wred(e); efx = wred(efx); efy = wred(efy); efz = wred(efz); dqa = wred(dqa);

    if (lane == 0) {
        double tot = 0.5 * e;
        // polarization: -1/2 E.alpha.E with alpha = Ra diag Ra^T  -> v = Ra^T E
        double v0 = (double)Ra[0][0] * efx + (double)Ra[1][0] * efy + (double)Ra[2][0] * efz;
        double v1 = (double)Ra[0][1] * efx + (double)Ra[1][1] * efy + (double)Ra[2][1] * efz;
        double v2 = (double)Ra[0][2] * efx + (double)Ra[1][2] * efy + (double)Ra[2][2] * efz;
        tot -= 0.5 * ((ta ? AD_[1][0] : AD_[0][0]) * v0 * v0 +
                      (ta ? AD_[1][1] : AD_[0][1]) * v1 * v1 +
                      (ta ? AD_[1][2] : AD_[0][2]) * v2 * v2);
        // indirect charge transfer
        tot += 0.5 * (ta ? ETA_[1] : ETA_[0]) * dqa * dqa;

        // bonded terms: O-blocks handle their water (f64)
        if (ta == 0) {
            double bxd[3][3], bid[3][3];
            load_boxd(box, bxd, bid);
            d3 cO = getcd(coords, 3 * wa);
            d3 b1 = pbcd(subd(getcd(coords, 3 * wa + 1), cO), bxd, bid);
            d3 b2 = pbcd(subd(getcd(coords, 3 * wa + 2), cO), bxd, bid);
            double l1 = sqrt(dotd(b1, b1)), l2 = sqrt(dotd(b2, b2));
            double beta = sqrt(K_B / (2.0 * D_M));
            double x1 = 1.0 - exp(-beta * (l1 - B_EQ));
            double x2 = 1.0 - exp(-beta * (l2 - B_EQ));
            tot += D_M * (x1 * x1 + x2 * x2);
            tot += K_BB * (l1 - B_EQ) * (l2 - B_EQ);
            double cang = dotd(b1, b2) / (l1 * l2);
            cang = fmin(fmax(cang, -1.0 + 1e-7), 1.0 - 1e-7);
            double th = acos(cang);
            double cte = cos(TH_EQ);
            tot += 0.5 * K_TH * (cang - cte) * (cang - cte);
            tot += K_BA * ((l1 - B_EQ) + (l2 - B_EQ)) * (th - TH_EQ);
        }
        atomicAdd(out, (float)tot);
    }
}

extern "C" void kernel_launch(void* const* d_in, const int* in_sizes, int n_in,
                              void* d_out, int out_size, void* d_ws, size_t ws_size,
                              hipStream_t stream) {
    const float* coords = (const float*)d_in[0];
    const float* box    = (const float*)d_in[1];
    int N = in_sizes[0] / 3;  // atoms (768)
    float* out = (float*)d_out;

    hipMemsetAsync(d_out, 0, sizeof(float), stream);
    k_fused<<<N, 64, 0, stream>>>(coords, box, out, N);
}

// Round 4
// 25.935 us; speedup vs baseline: 1.1265x; 1.1265x over previous
//
#include <hip/hip_runtime.h>
#include <math.h>

// ---------------- constants (atomic units) ----------------
constexpr double B2A   = 0.52917721067;
constexpr double H2KJ  = 2625.499638;
constexpr float  RCUT2F = (float)((10.0 / B2A) * (10.0 / B2A));

constexpr double Zc_[2]   = {3.61565, 0.93619};
constexpr double MONO_[2] = {-0.390896, 0.195448};
constexpr double QSH_[2]  = {MONO_[0] - Zc_[0], MONO_[1] - Zc_[1]};
constexpr double DIPO_[2][3] = {{0.0, 0.0, -0.094298},
                                {0.0910288, 0.0, -0.207851}};
constexpr double QS_[2][5] = {{-0.330685, 0.0, 0.0, 0.869923, 0.0},
                              {-0.0739388, 0.0929482, 0.0, 0.00532425, 0.0}};
constexpr double B_EL_[2]  = {2.13358, 2.33322};
constexpr double B_PA_[2]  = {2.1975, 1.96474};
constexpr double SPA_[2]   = {6.50923, 0.527804};
constexpr double KD_PA_[2] = {-5.61925, -0.515584};
constexpr double KQ_PA_[2] = {-1.56567, -0.440164};
constexpr double C6_[2]    = {35.8289, 1.98954};
constexpr double B_D_[2]   = {1.84302, 1.30993};
constexpr double AD_[2][3] = {{4.45992, 6.07259, 4.55391},
                              {2.22001, 1.66835, 0.183855}};
constexpr double ETA_[2]   = {6.18699e-06 * 2.0, 0.561535 * 2.0};
constexpr double B_XP_[2]  = {2.73582, 2.04028};
constexpr double SXP_[2]   = {1.26592, 0.200089};
constexpr double B_CT_[2]  = {1.89485, 2.36763};
constexpr double SACC_[2]  = {-0.67857, 1.36735};
constexpr double SDON_[2]  = {0.757752, 0.00888982};
constexpr double KD_DO_[2] = {-0.512036, -0.0511668};
constexpr double KQ_DO_[2] = {-0.208186, 0.0568152};
constexpr double EPS_OFF = 0.380979;

constexpr double D_M   = 524.265 / H2KJ;
constexpr double K_B   = 5098.15 / H2KJ * B2A * B2A;
constexpr double B_EQ  = 0.958413 / B2A;
constexpr double K_BB  = -61.1423 / H2KJ * B2A * B2A;
constexpr double K_BA  = -159.886 / H2KJ * B2A;
constexpr double TH_EQ = 104.4234 * M_PI / 180.0;
constexpr double K_TH  = 452.183 / H2KJ;
constexpr double SQ32  = 0.86602540378443864676;

// local-frame quadrupole (traceless Cartesian), /3 folded; q21s=q22s=0 -> only xx,yy,zz,xz
constexpr double QLXX_[2] = {(-0.5 * QS_[0][0] + SQ32 * QS_[0][3]) / 3.0,
                             (-0.5 * QS_[1][0] + SQ32 * QS_[1][3]) / 3.0};
constexpr double QLYY_[2] = {(-0.5 * QS_[0][0] - SQ32 * QS_[0][3]) / 3.0,
                             (-0.5 * QS_[1][0] - SQ32 * QS_[1][3]) / 3.0};
constexpr double QLZZ_[2] = {QS_[0][0] / 3.0, QS_[1][0] / 3.0};
constexpr double QLXZ_[2] = {SQ32 * QS_[0][1] / 3.0, SQ32 * QS_[1][1] / 3.0};
constexpr double DIP0_[2] = {DIPO_[0][0], DIPO_[1][0]};
constexpr double DIP2_[2] = {DIPO_[0][2], DIPO_[1][2]};

#define MAXN 768
#define NWAVE 4
#define TF(A, t) ((t) ? (float)A[1] : (float)A[0])
#define S(x) (tb ? x##1 : x##0)

// ---------------- f32 vec helpers ----------------
struct f3 { float x, y, z; };
__device__ inline f3 operator-(f3 a, f3 b) { return {a.x - b.x, a.y - b.y, a.z - b.z}; }
__device__ inline f3 operator+(f3 a, f3 b) { return {a.x + b.x, a.y + b.y, a.z + b.z}; }
__device__ inline f3 operator*(f3 a, float s) { return {a.x * s, a.y * s, a.z * s}; }
__device__ inline float dotf(f3 a, f3 b) { return a.x * b.x + a.y * b.y + a.z * b.z; }
__device__ inline f3 crossf(f3 a, f3 b) {
    return {a.y * b.z - a.z * b.y, a.z * b.x - a.x * b.z, a.x * b.y - a.y * b.x};
}
__device__ inline f3 normf(f3 a) { float s = rsqrtf(dotf(a, a)); return a * s; }
__device__ inline f3 getcf(const float* c, int i) {
    return {c[3 * i], c[3 * i + 1], c[3 * i + 2]};
}
__device__ inline void load_boxf(const float* box, float bx[3][3], float bi[3][3]) {
    for (int i = 0; i < 3; ++i)
        for (int j = 0; j < 3; ++j) bx[i][j] = box[i * 3 + j];
    float a = bx[0][0], b = bx[0][1], c = bx[0][2];
    float d = bx[1][0], e = bx[1][1], f = bx[1][2];
    float g = bx[2][0], h = bx[2][1], i2 = bx[2][2];
    float A =  (e * i2 - f * h), B = -(d * i2 - f * g), C =  (d * h - e * g);
    float D = -(b * i2 - c * h), E =  (a * i2 - c * g), F = -(a * h - b * g);
    float G =  (b * f - c * e),  H = -(a * f - c * d),  I =  (a * e - b * d);
    float s = 1.0f / (a * A + b * B + c * C);
    bi[0][0] = A * s; bi[0][1] = D * s; bi[0][2] = G * s;
    bi[1][0] = B * s; bi[1][1] = E * s; bi[1][2] = H * s;
    bi[2][0] = C * s; bi[2][1] = F * s; bi[2][2] = I * s;
}
__device__ inline f3 pbcf(f3 d, const float bx[3][3], const float bi[3][3]) {
    float s0 = rintf(d.x * bi[0][0] + d.y * bi[1][0] + d.z * bi[2][0]);
    float s1 = rintf(d.x * bi[0][1] + d.y * bi[1][1] + d.z * bi[2][1]);
    float s2 = rintf(d.x * bi[0][2] + d.y * bi[1][2] + d.z * bi[2][2]);
    d.x -= s0 * bx[0][0] + s1 * bx[1][0] + s2 * bx[2][0];
    d.y -= s0 * bx[0][1] + s1 * bx[1][1] + s2 * bx[2][1];
    d.z -= s0 * bx[0][2] + s1 * bx[1][2] + s2 * bx[2][2];
    return d;
}
__device__ inline float f1mf(float u) { return -__expf(-u) * (1.0f + 0.5f * u); }  // f1 - 1

// ---------------- f64 helpers (bonded terms only) ----------------
struct d3 { double x, y, z; };
__device__ inline d3 subd(d3 a, d3 b) { return {a.x - b.x, a.y - b.y, a.z - b.z}; }
__device__ inline double dotd(d3 a, d3 b) { return a.x * b.x + a.y * b.y + a.z * b.z; }
__device__ inline d3 getcd(const float* c, int i) {
    return {(double)c[3 * i], (double)c[3 * i + 1], (double)c[3 * i + 2]};
}
__device__ inline void load_boxd(const float* box, double bx[3][3], double bi[3][3]) {
    for (int i = 0; i < 3; ++i)
        for (int j = 0; j < 3; ++j) bx[i][j] = (double)box[i * 3 + j];
    double a = bx[0][0], b = bx[0][1], c = bx[0][2];
    double d = bx[1][0], e = bx[1][1], f = bx[1][2];
    double g = bx[2][0], h = bx[2][1], i2 = bx[2][2];
    double A =  (e * i2 - f * h), B = -(d * i2 - f * g), C =  (d * h - e * g);
    double D = -(b * i2 - c * h), E =  (a * i2 - c * g), F = -(a * h - b * g);
    double G =  (b * f - c * e),  H = -(a * f - c * d),  I =  (a * e - b * d);
    double s = 1.0 / (a * A + b * B + c * C);
    bi[0][0] = A * s; bi[0][1] = D * s; bi[0][2] = G * s;
    bi[1][0] = B * s; bi[1][1] = E * s; bi[1][2] = H * s;
    bi[2][0] = C * s; bi[2][1] = F * s; bi[2][2] = I * s;
}
__device__ inline d3 pbcd(d3 d, const double bx[3][3], const double bi[3][3]) {
    double s0 = rint(d.x * bi[0][0] + d.y * bi[1][0] + d.z * bi[2][0]);
    double s1 = rint(d.x * bi[0][1] + d.y * bi[1][1] + d.z * bi[2][1]);
    double s2 = rint(d.x * bi[0][2] + d.y * bi[1][2] + d.z * bi[2][2]);
    d.x -= s0 * bx[0][0] + s1 * bx[1][0] + s2 * bx[2][0];
    d.y -= s0 * bx[0][1] + s1 * bx[1][1] + s2 * bx[2][1];
    d.z -= s0 * bx[0][2] + s1 * bx[1][2] + s2 * bx[2][2];
    return d;
}

// ---------------- frame (local axes) ----------------
__device__ inline void calc_frame(const float* coords, const float bx[3][3],
                                  const float bi[3][3], int n, float R[3][3], int* tt) {
    int w = n / 3, m = n - w * 3, o = w * 3;
    int zat = (m == 0) ? n + 1 : o;
    int xat = (m == 0) ? n + 2 : ((m == 1) ? n + 1 : n - 1);
    f3 cn = getcf(coords, n);
    f3 uz = normf(pbcf(getcf(coords, zat) - cn, bx, bi));
    f3 ux = normf(pbcf(getcf(coords, xat) - cn, bx, bi));
    f3 zax = (m == 0) ? normf(uz + ux) : uz;
    f3 xax = normf(ux - zax * dotf(ux, zax));
    f3 yax = crossf(zax, xax);
    R[0][0] = xax.x; R[0][1] = yax.x; R[0][2] = zax.x;
    R[1][0] = xax.y; R[1][1] = yax.y; R[1][2] = zax.y;
    R[2][0] = xax.z; R[2][1] = yax.z; R[2][2] = zax.z;
    *tt = (m == 0) ? 0 : 1;
}

__device__ inline double wred(double v) {
    for (int off = 32; off > 0; off >>= 1) v += __shfl_xor(v, off);
    return v;
}

// =============== single fused kernel: block(256) per atom, 4 waves ===============
__global__ void __launch_bounds__(256, 3)
k_fused(const float* __restrict__ coords, const float* __restrict__ box,
        float* __restrict__ out, int N) {
    __shared__ float  sh_muQ[MAXN * 9];   // per-atom: mu[3], Q[xx,xy,xz,yy,yz,zz]
    __shared__ float4 sh_list[MAXN];      // per-wave compacted (dr, b) segments
    __shared__ double sh_red[NWAVE * 5];

    int a = blockIdx.x;
    int tid = threadIdx.x;
    int w = tid >> 6, lane = tid & 63;
    float bx[3][3], bi[3][3];
    load_boxf(box, bx, bi);

    int wa = a / 3;
    int ta = (a - wa * 3) ? 1 : 0;
    f3 ca = getcf(coords, a);

    // ---- fill phase: all atoms' global-frame mu + Q into LDS ----
    for (int i = tid; i < N; i += 256) {
        float R[3][3]; int t;
        calc_frame(coords, bx, bi, i, R, &t);
        float d0 = TF(DIP0_, t), d2 = TF(DIP2_, t);
        float* M = &sh_muQ[i * 9];
        M[0] = R[0][0] * d0 + R[0][2] * d2;
        M[1] = R[1][0] * d0 + R[1][2] * d2;
        M[2] = R[2][0] * d0 + R[2][2] * d2;
        float qlxx = TF(QLXX_, t), qlyy = TF(QLYY_, t), qlzz = TF(QLZZ_, t), qlxz = TF(QLXZ_, t);
        float Bq[3][3];
        for (int p = 0; p < 3; ++p) {
            Bq[p][0] = R[p][0] * qlxx + R[p][2] * qlxz;
            Bq[p][1] = R[p][1] * qlyy;
            Bq[p][2] = R[p][0] * qlxz + R[p][2] * qlzz;
        }
        M[3] = Bq[0][0] * R[0][0] + Bq[0][1] * R[0][1] + Bq[0][2] * R[0][2];  // xx
        M[4] = Bq[0][0] * R[1][0] + Bq[0][1] * R[1][1] + Bq[0][2] * R[1][2];  // xy
        M[5] = Bq[0][0] * R[2][0] + Bq[0][1] * R[2][1] + Bq[0][2] * R[2][2];  // xz
        M[6] = Bq[1][0] * R[1][0] + Bq[1][1] * R[1][1] + Bq[1][2] * R[1][2];  // yy
        M[7] = Bq[1][0] * R[2][0] + Bq[1][1] * R[2][1] + Bq[1][2] * R[2][2];  // yz
        M[8] = Bq[2][0] * R[2][0] + Bq[2][1] * R[2][1] + Bq[2][2] * R[2][2];  // zz
    }

    // ---- phase 1: per-wave cutoff compaction into own LDS segment ----
    int chunks = (N + 64 * NWAVE - 1) / (64 * NWAVE);   // chunks per wave
    int seg = chunks * 64;
    int base = w * seg;
    int cnt = 0;
    for (int k = 0; k < chunks; ++k) {
        int b = base + k * 64 + lane;
        bool pred = false;
        f3 dr = {0.f, 0.f, 0.f};
        if (b < N) {
            int wb = b / 3;
            dr = pbcf(getcf(coords, b) - ca, bx, bi);
            pred = (wb != wa) && (dotf(dr, dr) < RCUT2F);
        }
        unsigned long long mask = __ballot(pred);
        int pref = __popcll(mask & ((1ull << lane) - 1ull));
        if (pred) sh_list[base + cnt + pref] = make_float4(dr.x, dr.y, dr.z, __int_as_float(b));
        cnt += __popcll(mask);
    }

    __syncthreads();   // sh_muQ fill complete; sh_list segment is wave-local

    // ---- type-pair dual constants ----
    float Zi = TF(Zc_, ta), qi = TF(QSH_, ta), qti = Zi + qi;
    float beli = TF(B_EL_, ta);
    float belj0 = (float)B_EL_[0], belj1 = (float)B_EL_[1];
    float bije0 = sqrtf(beli * belj0), bije1 = sqrtf(beli * belj1);
    float qtj0 = (float)(Zc_[0] + QSH_[0]), qtj1 = (float)(Zc_[1] + QSH_[1]);
    float Ziqj0 = Zi * (float)QSH_[0], Ziqj1 = Zi * (float)QSH_[1];
    float Zjqi0 = (float)Zc_[0] * qi, Zjqi1 = (float)Zc_[1] * qi;
    float qiqj0 = qi * (float)QSH_[0], qiqj1 = qi * (float)QSH_[1];
    float qq0 = qti * qtj0, qq1 = qti * qtj1;
    float sacci = TF(SACC_, ta);
    float saccj0 = (float)SACC_[0], saccj1 = (float)SACC_[1];
    float sdi = TF(SDON_, ta), kddi = TF(KD_DO_, ta), kqdi = TF(KQ_DO_, ta);
    float sdj0 = (float)SDON_[0], sdj1 = (float)SDON_[1];
    float kddj0 = (float)KD_DO_[0], kddj1 = (float)KD_DO_[1];
    float kqdj0 = (float)KQ_DO_[0], kqdj1 = (float)KQ_DO_[1];
    float bctt = TF(B_CT_, ta);
    float bijct0 = sqrtf(bctt * (float)B_CT_[0]), bijct1 = sqrtf(bctt * (float)B_CT_[1]);
    float inve0 = (ta == 0) ? 1e-15f : (float)(1.0 / EPS_OFF);
    float inve1 = (ta == 1) ? 1e-15f : (float)(1.0 / EPS_OFF);
    float spi = TF(SPA_, ta), kdpi = TF(KD_PA_, ta), kqpi = TF(KQ_PA_, ta);
    float spj0 = (float)SPA_[0], spj1 = (float)SPA_[1];
    float kdpj0 = (float)KD_PA_[0], kdpj1 = (float)KD_PA_[1];
    float kqpj0 = (float)KQ_PA_[0], kqpj1 = (float)KQ_PA_[1];
    float bpat = TF(B_PA_, ta);
    float bijpa0 = sqrtf(bpat * (float)B_PA_[0]), bijpa1 = sqrtf(bpat * (float)B_PA_[1]);
    float bxpt = TF(B_XP_, ta);
    float bijxp0 = sqrtf(bxpt * (float)B_XP_[0]), bijxp1 = sqrtf(bxpt * (float)B_XP_[1]);
    float sxpi = TF(SXP_, ta);
    float cxp0 = sxpi * (float)SXP_[0], cxp1 = sxpi * (float)SXP_[1];
    float bdt = TF(B_D_, ta);
    float bijd0 = sqrtf(bdt * (float)B_D_[0]), bijd1 = sqrtf(bdt * (float)B_D_[1]);
    float c6t = TF(C6_, ta);
    float c60 = sqrtf(c6t * (float)C6_[0]), c61 = sqrtf(c6t * (float)C6_[1]);

    const float* MA = &sh_muQ[a * 9];
    f3 mua = {MA[0], MA[1], MA[2]};
    float Qaxx = MA[3], Qaxy = MA[4], Qaxz = MA[5], Qayy = MA[6], Qayz = MA[7], Qazz = MA[8];

    // ---- phase 2: dense pair loop over this wave's survivors ----
    double e = 0.0, efx = 0.0, efy = 0.0, efz = 0.0, dqa = 0.0;
    for (int i = lane; i < cnt; i += 64) {
        float4 E4 = sh_list[base + i];
        f3 dr = {E4.x, E4.y, E4.z};
        int b = __float_as_int(E4.w);
        int wb = b / 3;
        int tb = (b - wb * 3) ? 1 : 0;
        float r2 = dotf(dr, dr);
        float invr = rsqrtf(r2);
        float r = r2 * invr;
        f3 nv = dr * invr;
        float invr2 = invr * invr, invr3 = invr2 * invr;

        const float* MB = &sh_muQ[b * 9];
        f3 mub = {MB[0], MB[1], MB[2]};
        float muin = dotf(mua, nv), mujn = dotf(mub, nv);
        float nQni = Qaxx * nv.x * nv.x + Qayy * nv.y * nv.y + Qazz * nv.z * nv.z +
                     2.f * (Qaxy * nv.x * nv.y + Qaxz * nv.x * nv.z + Qayz * nv.y * nv.z);
        float nQnj = MB[3] * nv.x * nv.x + MB[6] * nv.y * nv.y + MB[8] * nv.z * nv.z +
                     2.f * (MB[4] * nv.x * nv.y + MB[5] * nv.x * nv.z + MB[7] * nv.y * nv.z);

        // permanent electrostatics (e_qq rearranged: no large-term cancellation)
        float fdm = f1mf(S(bije) * r);
        float fd = 1.f + fdm;
        float ep = (S(qq) + S(Ziqj) * f1mf(S(belj) * r) + S(Zjqi) * f1mf(beli * r) +
                    S(qiqj) * fdm) * invr;
        ep += fd * (S(qtj) * muin - qti * mujn) * invr2;
        ep += fd * (dotf(mua, mub) - 3.f * muin * mujn) * invr3;
        ep += 3.f * fd * (qti * nQnj + S(qtj) * nQni) * invr3;

        // field at atom a
        float cc = -S(qtj) * invr2 + 3.f * mujn * invr3;
        efx += (double)(fd * (cc * nv.x - mub.x * invr3));
        efy += (double)(fd * (cc * nv.y - mub.y * invr3));
        efz += (double)(fd * (cc * nv.z - mub.z * invr3));

        // charge transfer
        float sdon_i = sdi + kddi * muin + kqdi * nQni;
        float sdon_j = S(sdj) - S(kddj) * mujn + S(kqdj) * nQnj;
        float sct_r = __expf(-S(bijct) * r) * invr;
        ep -= (sdon_i * S(saccj) + sdon_j * sacci) * sct_r;
        dqa += (double)(sdon_j * sacci * sct_r * S(inve));

        // Pauli repulsion
        float si = spi + kdpi * muin + kqpi * nQni;
        float sj = S(spj) - S(kdpj) * mujn + S(kqpj) * nQnj;
        ep += si * sj * __expf(-S(bijpa) * r) * invr;

        // exchange polarization
        ep -= S(cxp) * __expf(-S(bijxp) * r) * invr;

        // Tang-Toennies dispersion
        float u = S(bijd) * r;
        float poly = 1.f + u * (1.f + u * (0.5f + u * (0.16666667f + u * (4.1666667e-2f +
                     u * (8.3333333e-3f + u * 1.3888889e-3f)))));
        ep -= (1.f - __expf(-u) * poly) * S(c6) * invr3 * invr3;

        e += (double)ep;
    }

    // ---- reduction: wave shuffle, then cross-wave via LDS ----
    e = wred(e); efx = wred(efx); efy = wred(efy); efz = wred(efz); dqa = wred(dqa);
    if (lane == 0) {
        sh_red[w * 5 + 0] = e;
        sh_red[w * 5 + 1] = efx;
        sh_red[w * 5 + 2] = efy;
        sh_red[w * 5 + 3] = efz;
        sh_red[w * 5 + 4] = dqa;
    }
    __syncthreads();

    if (tid == 0) {
        double se = 0, sx = 0, sy = 0, sz = 0, sq = 0;
        for (int k = 0; k < NWAVE; ++k) {
            se += sh_red[k * 5 + 0];
            sx += sh_red[k * 5 + 1];
            sy += sh_red[k * 5 + 2];
            sz += sh_red[k * 5 + 3];
            sq += sh_red[k * 5 + 4];
        }
        double tot = 0.5 * se;
        // polarization: -1/2 E.alpha.E, alpha = Ra diag Ra^T  -> v = Ra^T E
        float Ra[3][3]; int tt;
        calc_frame(coords, bx, bi, a, Ra, &tt);
        double v0 = (double)Ra[0][0] * sx + (double)Ra[1][0] * sy + (double)Ra[2][0] * sz;
        double v1 = (double)Ra[0][1] * sx + (double)Ra[1][1] * sy + (double)Ra[2][1] * sz;
        double v2 = (double)Ra[0][2] * sx + (double)Ra[1][2] * sy + (double)Ra[2][2] * sz;
        tot -= 0.5 * ((ta ? AD_[1][0] : AD_[0][0]) * v0 * v0 +
                      (ta ? AD_[1][1] : AD_[0][1]) * v1 * v1 +
                      (ta ? AD_[1][2] : AD_[0][2]) * v2 * v2);
        // indirect charge transfer
        tot += 0.5 * (ta ? ETA_[1] : ETA_[0]) * sq * sq;

        // bonded terms: O-blocks handle their water (f64)
        if (ta == 0) {
            double bxd[3][3], bid[3][3];
            load_boxd(box, bxd, bid);
            d3 cO = getcd(coords, 3 * wa);
            d3 b1 = pbcd(subd(getcd(coords, 3 * wa + 1), cO), bxd, bid);
            d3 b2 = pbcd(subd(getcd(coords, 3 * wa + 2), cO), bxd, bid);
            double l1 = sqrt(dotd(b1, b1)), l2 = sqrt(dotd(b2, b2));
            double beta = sqrt(K_B / (2.0 * D_M));
            double x1 = 1.0 - exp(-beta * (l1 - B_EQ));
            double x2 = 1.0 - exp(-beta * (l2 - B_EQ));
            tot += D_M * (x1 * x1 + x2 * x2);
            tot += K_BB * (l1 - B_EQ) * (l2 - B_EQ);
            double cang = dotd(b1, b2) / (l1 * l2);
            cang = fmin(fmax(cang, -1.0 + 1e-7), 1.0 - 1e-7);
            double th = acos(cang);
            double cte = cos(TH_EQ);
            tot += 0.5 * K_TH * (cang - cte) * (cang - cte);
            tot += K_BA * ((l1 - B_EQ) + (l2 - B_EQ)) * (th - TH_EQ);
        }
        atomicAdd(out, (float)tot);
    }
}

extern "C" void kernel_launch(void* const* d_in, const int* in_sizes, int n_in,
                              void* d_out, int out_size, void* d_ws, size_t ws_size,
                              hipStream_t stream) {
    const float* coords = (const float*)d_in[0];
    const float* box    = (const float*)d_in[1];
    int N = in_sizes[0] / 3;  // atoms (768)
    float* out = (float*)d_out;

    hipMemsetAsync(d_out, 0, sizeof(float), stream);
    k_fused<<<N, 256, 0, stream>>>(coords, box, out, N);
}

// Round 5
// 18.294 us; speedup vs baseline: 1.5969x; 1.4176x over previous
//
#include <hip/hip_runtime.h>
#include <math.h>

// ---------------- constants (atomic units) ----------------
constexpr double B2A   = 0.52917721067;
constexpr double H2KJ  = 2625.499638;
constexpr float  RCUT2F = (float)((10.0 / B2A) * (10.0 / B2A));

constexpr double Zc_[2]   = {3.61565, 0.93619};
constexpr double MONO_[2] = {-0.390896, 0.195448};
constexpr double QSH_[2]  = {MONO_[0] - Zc_[0], MONO_[1] - Zc_[1]};
constexpr double DIPO_[2][3] = {{0.0, 0.0, -0.094298},
                                {0.0910288, 0.0, -0.207851}};
constexpr double QS_[2][5] = {{-0.330685, 0.0, 0.0, 0.869923, 0.0},
                              {-0.0739388, 0.0929482, 0.0, 0.00532425, 0.0}};
constexpr double B_EL_[2]  = {2.13358, 2.33322};
constexpr double B_PA_[2]  = {2.1975, 1.96474};
constexpr double SPA_[2]   = {6.50923, 0.527804};
constexpr double KD_PA_[2] = {-5.61925, -0.515584};
constexpr double KQ_PA_[2] = {-1.56567, -0.440164};
constexpr double C6_[2]    = {35.8289, 1.98954};
constexpr double B_D_[2]   = {1.84302, 1.30993};
constexpr double AD_[2][3] = {{4.45992, 6.07259, 4.55391},
                              {2.22001, 1.66835, 0.183855}};
constexpr double ETA_[2]   = {6.18699e-06 * 2.0, 0.561535 * 2.0};
constexpr double B_XP_[2]  = {2.73582, 2.04028};
constexpr double SXP_[2]   = {1.26592, 0.200089};
constexpr double B_CT_[2]  = {1.89485, 2.36763};
constexpr double SACC_[2]  = {-0.67857, 1.36735};
constexpr double SDON_[2]  = {0.757752, 0.00888982};
constexpr double KD_DO_[2] = {-0.512036, -0.0511668};
constexpr double KQ_DO_[2] = {-0.208186, 0.0568152};
constexpr double EPS_OFF = 0.380979;

constexpr double D_M   = 524.265 / H2KJ;
constexpr double K_B   = 5098.15 / H2KJ * B2A * B2A;
constexpr double B_EQ  = 0.958413 / B2A;
constexpr double K_BB  = -61.1423 / H2KJ * B2A * B2A;
constexpr double K_BA  = -159.886 / H2KJ * B2A;
constexpr double TH_EQ = 104.4234 * M_PI / 180.0;
constexpr double K_TH  = 452.183 / H2KJ;
constexpr double SQ32  = 0.86602540378443864676;

// local-frame quadrupole (traceless Cartesian), /3 folded; q21s=q22s=0 -> only xx,yy,zz,xz
constexpr double QLXX_[2] = {(-0.5 * QS_[0][0] + SQ32 * QS_[0][3]) / 3.0,
                             (-0.5 * QS_[1][0] + SQ32 * QS_[1][3]) / 3.0};
constexpr double QLYY_[2] = {(-0.5 * QS_[0][0] - SQ32 * QS_[0][3]) / 3.0,
                             (-0.5 * QS_[1][0] - SQ32 * QS_[1][3]) / 3.0};
constexpr double QLZZ_[2] = {QS_[0][0] / 3.0, QS_[1][0] / 3.0};
constexpr double QLXZ_[2] = {SQ32 * QS_[0][1] / 3.0, SQ32 * QS_[1][1] / 3.0};
constexpr double DIP0_[2] = {DIPO_[0][0], DIPO_[1][0]};
constexpr double DIP2_[2] = {DIPO_[0][2], DIPO_[1][2]};

#define MAXN 768
#define NWAVE 4
#define TF(A, t) ((t) ? (float)A[1] : (float)A[0])
#define S(x) (tb ? x##1 : x##0)

// ---------------- f32 vec helpers ----------------
struct f3 { float x, y, z; };
__device__ inline f3 operator-(f3 a, f3 b) { return {a.x - b.x, a.y - b.y, a.z - b.z}; }
__device__ inline f3 operator+(f3 a, f3 b) { return {a.x + b.x, a.y + b.y, a.z + b.z}; }
__device__ inline f3 operator*(f3 a, float s) { return {a.x * s, a.y * s, a.z * s}; }
__device__ inline float dotf(f3 a, f3 b) { return a.x * b.x + a.y * b.y + a.z * b.z; }
__device__ inline f3 crossf(f3 a, f3 b) {
    return {a.y * b.z - a.z * b.y, a.z * b.x - a.x * b.z, a.x * b.y - a.y * b.x};
}
__device__ inline f3 normf(f3 a) { float s = rsqrtf(dotf(a, a)); return a * s; }
__device__ inline f3 getcf(const float* c, int i) {
    return {c[3 * i], c[3 * i + 1], c[3 * i + 2]};
}
__device__ inline void load_boxf(const float* box, float bx[3][3], float bi[3][3]) {
    for (int i = 0; i < 3; ++i)
        for (int j = 0; j < 3; ++j) bx[i][j] = box[i * 3 + j];
    float a = bx[0][0], b = bx[0][1], c = bx[0][2];
    float d = bx[1][0], e = bx[1][1], f = bx[1][2];
    float g = bx[2][0], h = bx[2][1], i2 = bx[2][2];
    float A =  (e * i2 - f * h), B = -(d * i2 - f * g), C =  (d * h - e * g);
    float D = -(b * i2 - c * h), E =  (a * i2 - c * g), F = -(a * h - b * g);
    float G =  (b * f - c * e),  H = -(a * f - c * d),  I =  (a * e - b * d);
    float s = 1.0f / (a * A + b * B + c * C);
    bi[0][0] = A * s; bi[0][1] = D * s; bi[0][2] = G * s;
    bi[1][0] = B * s; bi[1][1] = E * s; bi[1][2] = H * s;
    bi[2][0] = C * s; bi[2][1] = F * s; bi[2][2] = I * s;
}
__device__ inline f3 pbcf(f3 d, const float bx[3][3], const float bi[3][3]) {
    float s0 = rintf(d.x * bi[0][0] + d.y * bi[1][0] + d.z * bi[2][0]);
    float s1 = rintf(d.x * bi[0][1] + d.y * bi[1][1] + d.z * bi[2][1]);
    float s2 = rintf(d.x * bi[0][2] + d.y * bi[1][2] + d.z * bi[2][2]);
    d.x -= s0 * bx[0][0] + s1 * bx[1][0] + s2 * bx[2][0];
    d.y -= s0 * bx[0][1] + s1 * bx[1][1] + s2 * bx[2][1];
    d.z -= s0 * bx[0][2] + s1 * bx[1][2] + s2 * bx[2][2];
    return d;
}
__device__ inline float f1mf(float u) { return -__expf(-u) * (1.0f + 0.5f * u); }  // f1 - 1

// ---------------- f64 helpers (bonded terms only) ----------------
struct d3 { double x, y, z; };
__device__ inline d3 subd(d3 a, d3 b) { return {a.x - b.x, a.y - b.y, a.z - b.z}; }
__device__ inline double dotd(d3 a, d3 b) { return a.x * b.x + a.y * b.y + a.z * b.z; }
__device__ inline d3 getcd(const float* c, int i) {
    return {(double)c[3 * i], (double)c[3 * i + 1], (double)c[3 * i + 2]};
}
__device__ inline void load_boxd(const float* box, double bx[3][3], double bi[3][3]) {
    for (int i = 0; i < 3; ++i)
        for (int j = 0; j < 3; ++j) bx[i][j] = (double)box[i * 3 + j];
    double a = bx[0][0], b = bx[0][1], c = bx[0][2];
    double d = bx[1][0], e = bx[1][1], f = bx[1][2];
    double g = bx[2][0], h = bx[2][1], i2 = bx[2][2];
    double A =  (e * i2 - f * h), B = -(d * i2 - f * g), C =  (d * h - e * g);
    double D = -(b * i2 - c * h), E =  (a * i2 - c * g), F = -(a * h - b * g);
    double G =  (b * f - c * e),  H = -(a * f - c * d),  I =  (a * e - b * d);
    double s = 1.0 / (a * A + b * B + c * C);
    bi[0][0] = A * s; bi[0][1] = D * s; bi[0][2] = G * s;
    bi[1][0] = B * s; bi[1][1] = E * s; bi[1][2] = H * s;
    bi[2][0] = C * s; bi[2][1] = F * s; bi[2][2] = I * s;
}
__device__ inline d3 pbcd(d3 d, const double bx[3][3], const double bi[3][3]) {
    double s0 = rint(d.x * bi[0][0] + d.y * bi[1][0] + d.z * bi[2][0]);
    double s1 = rint(d.x * bi[0][1] + d.y * bi[1][1] + d.z * bi[2][1]);
    double s2 = rint(d.x * bi[0][2] + d.y * bi[1][2] + d.z * bi[2][2]);
    d.x -= s0 * bx[0][0] + s1 * bx[1][0] + s2 * bx[2][0];
    d.y -= s0 * bx[0][1] + s1 * bx[1][1] + s2 * bx[2][1];
    d.z -= s0 * bx[0][2] + s1 * bx[1][2] + s2 * bx[2][2];
    return d;
}

// ---------------- frame (local axes) ----------------
__device__ inline void calc_frame(const float* coords, const float bx[3][3],
                                  const float bi[3][3], int n, float R[3][3], int* tt) {
    int w = n / 3, m = n - w * 3, o = w * 3;
    int zat = (m == 0) ? n + 1 : o;
    int xat = (m == 0) ? n + 2 : ((m == 1) ? n + 1 : n - 1);
    f3 cn = getcf(coords, n);
    f3 uz = normf(pbcf(getcf(coords, zat) - cn, bx, bi));
    f3 ux = normf(pbcf(getcf(coords, xat) - cn, bx, bi));
    f3 zax = (m == 0) ? normf(uz + ux) : uz;
    f3 xax = normf(ux - zax * dotf(ux, zax));
    f3 yax = crossf(zax, xax);
    R[0][0] = xax.x; R[0][1] = yax.x; R[0][2] = zax.x;
    R[1][0] = xax.y; R[1][1] = yax.y; R[1][2] = zax.y;
    R[2][0] = xax.z; R[2][1] = yax.z; R[2][2] = zax.z;
    *tt = (m == 0) ? 0 : 1;
}

// rotated multipoles: M = [mu0,mu1,mu2, Qxx,Qxy,Qxz,Qyy,Qyz,Qzz]
__device__ inline void rot_muQ(const float R[3][3], int t, float M[9]) {
    float d0 = TF(DIP0_, t), d2 = TF(DIP2_, t);
    M[0] = R[0][0] * d0 + R[0][2] * d2;
    M[1] = R[1][0] * d0 + R[1][2] * d2;
    M[2] = R[2][0] * d0 + R[2][2] * d2;
    float qlxx = TF(QLXX_, t), qlyy = TF(QLYY_, t), qlzz = TF(QLZZ_, t), qlxz = TF(QLXZ_, t);
    float Bq[3][3];
    for (int p = 0; p < 3; ++p) {
        Bq[p][0] = R[p][0] * qlxx + R[p][2] * qlxz;
        Bq[p][1] = R[p][1] * qlyy;
        Bq[p][2] = R[p][0] * qlxz + R[p][2] * qlzz;
    }
    M[3] = Bq[0][0] * R[0][0] + Bq[0][1] * R[0][1] + Bq[0][2] * R[0][2];
    M[4] = Bq[0][0] * R[1][0] + Bq[0][1] * R[1][1] + Bq[0][2] * R[1][2];
    M[5] = Bq[0][0] * R[2][0] + Bq[0][1] * R[2][1] + Bq[0][2] * R[2][2];
    M[6] = Bq[1][0] * R[1][0] + Bq[1][1] * R[1][1] + Bq[1][2] * R[1][2];
    M[7] = Bq[1][0] * R[2][0] + Bq[1][1] * R[2][1] + Bq[1][2] * R[2][2];
    M[8] = Bq[2][0] * R[2][0] + Bq[2][1] * R[2][1] + Bq[2][2] * R[2][2];
}

__device__ inline float wredf(float v) {
    for (int off = 32; off > 0; off >>= 1) v += __shfl_xor(v, off);
    return v;
}
__device__ inline double wredd(double v) {
    for (int off = 32; off > 0; off >>= 1) v += __shfl_xor(v, off);
    return v;
}

// =============== kernel 1: block(256, 4 waves) per atom ===============
__global__ void __launch_bounds__(256, 3)
k_main(const float* __restrict__ coords, const float* __restrict__ box,
       double* __restrict__ wsd, int N) {
    __shared__ float4 sh_list[MAXN];      // per-wave compacted (dr, b) segments
    __shared__ float  sh_muQ[MAXN * 9];   // multipoles of survivors, slot-parallel
    __shared__ double sh_red[NWAVE * 5];

    int a = blockIdx.x;
    int tid = threadIdx.x;
    int w = tid >> 6, lane = tid & 63;
    float bx[3][3], bi[3][3];
    load_boxf(box, bx, bi);

    int wa = a / 3;
    int ta = (a - wa * 3) ? 1 : 0;
    f3 ca = getcf(coords, a);

    // own-atom frame + multipoles (uniform across block)
    float Ra[3][3]; int tt0;
    calc_frame(coords, bx, bi, a, Ra, &tt0);
    float MA[9];
    rot_muQ(Ra, ta, MA);
    f3 mua = {MA[0], MA[1], MA[2]};
    float Qaxx = MA[3], Qaxy = MA[4], Qaxz = MA[5], Qayy = MA[6], Qayz = MA[7], Qazz = MA[8];

    // ---- phase 1: per-wave cutoff compaction into own LDS segment ----
    int chunks = (N + 64 * NWAVE - 1) / (64 * NWAVE);
    int seg = chunks * 64;
    int base = w * seg;
    int cnt = 0;
    for (int k = 0; k < chunks; ++k) {
        int b = base + k * 64 + lane;
        bool pred = false;
        f3 dr = {0.f, 0.f, 0.f};
        if (b < N) {
            int wb = b / 3;
            dr = pbcf(getcf(coords, b) - ca, bx, bi);
            pred = (wb != wa) && (dotf(dr, dr) < RCUT2F);
        }
        unsigned long long mask = __ballot(pred);
        int pref = __popcll(mask & ((1ull << lane) - 1ull));
        if (pred) sh_list[base + cnt + pref] = make_float4(dr.x, dr.y, dr.z, __int_as_float(b));
        cnt += __popcll(mask);
    }

    // ---- phase 1b: multipoles for SURVIVORS only (wave-local slots) ----
    for (int i = lane; i < cnt; i += 64) {
        int b = __float_as_int(sh_list[base + i].w);
        float Rb[3][3]; int tb;
        calc_frame(coords, bx, bi, b, Rb, &tb);
        float MB[9];
        rot_muQ(Rb, tb, MB);
        float* dst = &sh_muQ[(base + i) * 9];
        for (int k = 0; k < 9; ++k) dst[k] = MB[k];
    }

    // ---- type-pair dual constants ----
    float Zi = TF(Zc_, ta), qi = TF(QSH_, ta), qti = Zi + qi;
    float beli = TF(B_EL_, ta);
    float belj0 = (float)B_EL_[0], belj1 = (float)B_EL_[1];
    float bije0 = sqrtf(beli * belj0), bije1 = sqrtf(beli * belj1);
    float qtj0 = (float)(Zc_[0] + QSH_[0]), qtj1 = (float)(Zc_[1] + QSH_[1]);
    float Ziqj0 = Zi * (float)QSH_[0], Ziqj1 = Zi * (float)QSH_[1];
    float Zjqi0 = (float)Zc_[0] * qi, Zjqi1 = (float)Zc_[1] * qi;
    float qiqj0 = qi * (float)QSH_[0], qiqj1 = qi * (float)QSH_[1];
    float qq0 = qti * qtj0, qq1 = qti * qtj1;
    float sacci = TF(SACC_, ta);
    float saccj0 = (float)SACC_[0], saccj1 = (float)SACC_[1];
    float sdi = TF(SDON_, ta), kddi = TF(KD_DO_, ta), kqdi = TF(KQ_DO_, ta);
    float sdj0 = (float)SDON_[0], sdj1 = (float)SDON_[1];
    float kddj0 = (float)KD_DO_[0], kddj1 = (float)KD_DO_[1];
    float kqdj0 = (float)KQ_DO_[0], kqdj1 = (float)KQ_DO_[1];
    float bctt = TF(B_CT_, ta);
    float bijct0 = sqrtf(bctt * (float)B_CT_[0]), bijct1 = sqrtf(bctt * (float)B_CT_[1]);
    float inve0 = (ta == 0) ? 1e-15f : (float)(1.0 / EPS_OFF);
    float inve1 = (ta == 1) ? 1e-15f : (float)(1.0 / EPS_OFF);
    float spi = TF(SPA_, ta), kdpi = TF(KD_PA_, ta), kqpi = TF(KQ_PA_, ta);
    float spj0 = (float)SPA_[0], spj1 = (float)SPA_[1];
    float kdpj0 = (float)KD_PA_[0], kdpj1 = (float)KD_PA_[1];
    float kqpj0 = (float)KQ_PA_[0], kqpj1 = (float)KQ_PA_[1];
    float bpat = TF(B_PA_, ta);
    float bijpa0 = sqrtf(bpat * (float)B_PA_[0]), bijpa1 = sqrtf(bpat * (float)B_PA_[1]);
    float bxpt = TF(B_XP_, ta);
    float bijxp0 = sqrtf(bxpt * (float)B_XP_[0]), bijxp1 = sqrtf(bxpt * (float)B_XP_[1]);
    float sxpi = TF(SXP_, ta);
    float cxp0 = sxpi * (float)SXP_[0], cxp1 = sxpi * (float)SXP_[1];
    float bdt = TF(B_D_, ta);
    float bijd0 = sqrtf(bdt * (float)B_D_[0]), bijd1 = sqrtf(bdt * (float)B_D_[1]);
    float c6t = TF(C6_, ta);
    float c60 = sqrtf(c6t * (float)C6_[0]), c61 = sqrtf(c6t * (float)C6_[1]);

    // ---- phase 2: dense pair loop over this wave's survivors (f32 accum) ----
    float e = 0.f, efx = 0.f, efy = 0.f, efz = 0.f, dqa = 0.f;
    for (int i = lane; i < cnt; i += 64) {
        float4 E4 = sh_list[base + i];
        f3 dr = {E4.x, E4.y, E4.z};
        int b = __float_as_int(E4.w);
        int wb = b / 3;
        int tb = (b - wb * 3) ? 1 : 0;
        float r2 = dotf(dr, dr);
        float invr = rsqrtf(r2);
        float r = r2 * invr;
        f3 nv = dr * invr;
        float invr2 = invr * invr, invr3 = invr2 * invr;

        const float* MB = &sh_muQ[(base + i) * 9];
        f3 mub = {MB[0], MB[1], MB[2]};
        float muin = dotf(mua, nv), mujn = dotf(mub, nv);
        float nQni = Qaxx * nv.x * nv.x + Qayy * nv.y * nv.y + Qazz * nv.z * nv.z +
                     2.f * (Qaxy * nv.x * nv.y + Qaxz * nv.x * nv.z + Qayz * nv.y * nv.z);
        float nQnj = MB[3] * nv.x * nv.x + MB[6] * nv.y * nv.y + MB[8] * nv.z * nv.z +
                     2.f * (MB[4] * nv.x * nv.y + MB[5] * nv.x * nv.z + MB[7] * nv.y * nv.z);

        // permanent electrostatics (e_qq rearranged: no large-term cancellation)
        float fdm = f1mf(S(bije) * r);
        float fd = 1.f + fdm;
        float ep = (S(qq) + S(Ziqj) * f1mf(S(belj) * r) + S(Zjqi) * f1mf(beli * r) +
                    S(qiqj) * fdm) * invr;
        ep += fd * (S(qtj) * muin - qti * mujn) * invr2;
        ep += fd * (dotf(mua, mub) - 3.f * muin * mujn) * invr3;
        ep += 3.f * fd * (qti * nQnj + S(qtj) * nQni) * invr3;

        // field at atom a
        float cc = -S(qtj) * invr2 + 3.f * mujn * invr3;
        efx += fd * (cc * nv.x - mub.x * invr3);
        efy += fd * (cc * nv.y - mub.y * invr3);
        efz += fd * (cc * nv.z - mub.z * invr3);

        // charge transfer
        float sdon_i = sdi + kddi * muin + kqdi * nQni;
        float sdon_j = S(sdj) - S(kddj) * mujn + S(kqdj) * nQnj;
        float sct_r = __expf(-S(bijct) * r) * invr;
        ep -= (sdon_i * S(saccj) + sdon_j * sacci) * sct_r;
        dqa += sdon_j * sacci * sct_r * S(inve);

        // Pauli repulsion
        float si = spi + kdpi * muin + kqpi * nQni;
        float sj = S(spj) - S(kdpj) * mujn + S(kqpj) * nQnj;
        ep += si * sj * __expf(-S(bijpa) * r) * invr;

        // exchange polarization
        ep -= S(cxp) * __expf(-S(bijxp) * r) * invr;

        // Tang-Toennies dispersion
        float u = S(bijd) * r;
        float poly = 1.f + u * (1.f + u * (0.5f + u * (0.16666667f + u * (4.1666667e-2f +
                     u * (8.3333333e-3f + u * 1.3888889e-3f)))));
        ep -= (1.f - __expf(-u) * poly) * S(c6) * invr3 * invr3;

        e += ep;
    }

    // ---- reduction: wave shuffle (f32), then cross-wave via LDS (f64) ----
    e = wredf(e); efx = wredf(efx); efy = wredf(efy); efz = wredf(efz); dqa = wredf(dqa);
    if (lane == 0) {
        sh_red[w * 5 + 0] = (double)e;
        sh_red[w * 5 + 1] = (double)efx;
        sh_red[w * 5 + 2] = (double)efy;
        sh_red[w * 5 + 3] = (double)efz;
        sh_red[w * 5 + 4] = (double)dqa;
    }
    __syncthreads();

    if (tid == 0) {
        double se = 0, sx = 0, sy = 0, sz = 0, sq = 0;
        for (int k = 0; k < NWAVE; ++k) {
            se += sh_red[k * 5 + 0];
            sx += sh_red[k * 5 + 1];
            sy += sh_red[k * 5 + 2];
            sz += sh_red[k * 5 + 3];
            sq += sh_red[k * 5 + 4];
        }
        double tot = 0.5 * se;
        // polarization: -1/2 E.alpha.E, alpha = Ra diag Ra^T  -> v = Ra^T E
        double v0 = (double)Ra[0][0] * sx + (double)Ra[1][0] * sy + (double)Ra[2][0] * sz;
        double v1 = (double)Ra[0][1] * sx + (double)Ra[1][1] * sy + (double)Ra[2][1] * sz;
        double v2 = (double)Ra[0][2] * sx + (double)Ra[1][2] * sy + (double)Ra[2][2] * sz;
        tot -= 0.5 * ((ta ? AD_[1][0] : AD_[0][0]) * v0 * v0 +
                      (ta ? AD_[1][1] : AD_[0][1]) * v1 * v1 +
                      (ta ? AD_[1][2] : AD_[0][2]) * v2 * v2);
        // indirect charge transfer
        tot += 0.5 * (ta ? ETA_[1] : ETA_[0]) * sq * sq;

        // bonded terms: O-blocks handle their water (f64)
        if (ta == 0) {
            double bxd[3][3], bid[3][3];
            load_boxd(box, bxd, bid);
            d3 cO = getcd(coords, 3 * wa);
            d3 b1 = pbcd(subd(getcd(coords, 3 * wa + 1), cO), bxd, bid);
            d3 b2 = pbcd(subd(getcd(coords, 3 * wa + 2), cO), bxd, bid);
            double l1 = sqrt(dotd(b1, b1)), l2 = sqrt(dotd(b2, b2));
            double beta = sqrt(K_B / (2.0 * D_M));
            double x1 = 1.0 - exp(-beta * (l1 - B_EQ));
            double x2 = 1.0 - exp(-beta * (l2 - B_EQ));
            tot += D_M * (x1 * x1 + x2 * x2);
            tot += K_BB * (l1 - B_EQ) * (l2 - B_EQ);
            double cang = dotd(b1, b2) / (l1 * l2);
            cang = fmin(fmax(cang, -1.0 + 1e-7), 1.0 - 1e-7);
            double th = acos(cang);
            double cte = cos(TH_EQ);
            tot += 0.5 * K_TH * (cang - cte) * (cang - cte);
            tot += K_BA * ((l1 - B_EQ) + (l2 - B_EQ)) * (th - TH_EQ);
        }
        wsd[a] = tot;   // deterministic per-atom partial
    }
}

// =============== kernel 2: deterministic final reduce ===============
__global__ void __launch_bounds__(256) k_final(const double* __restrict__ wsd,
                                               float* __restrict__ out, int N) {
    int tid = threadIdx.x;
    int w = tid >> 6, lane = tid & 63;
    double v = 0.0;
    for (int i = tid; i < N; i += 256) v += wsd[i];
    v = wredd(v);
    __shared__ double s[4];
    if (lane == 0) s[w] = v;
    __syncthreads();
    if (tid == 0) out[0] = (float)(s[0] + s[1] + s[2] + s[3]);
}

extern "C" void kernel_launch(void* const* d_in, const int* in_sizes, int n_in,
                              void* d_out, int out_size, void* d_ws, size_t ws_size,
                              hipStream_t stream) {
    const float* coords = (const float*)d_in[0];
    const float* box    = (const float*)d_in[1];
    int N = in_sizes[0] / 3;  // atoms (768)
    double* wsd = (double*)d_ws;
    float* out = (float*)d_out;

    k_main<<<N, 256, 0, stream>>>(coords, box, wsd, N);
    k_final<<<1, 256, 0, stream>>>(wsd, out, N);
}